// Round 1
// baseline (218.544 us; speedup 1.0000x reference)
//
#include <hip/hip_runtime.h>

// Problem: CausalWanSelfAttention with DIM=1024, 64 heads of head-dim 1, N=2048.
// out[i,c] = sum_h w_out[c,h] * softmax_j<=i( q[i,h]*k[j,h]/8 ) . v[j,h]
//
// ws layout (floats):
//   wT     [1024][192]   = 196608   (w_qkv transposed: wT[k][f])
//   wOutT  [64][1024]    = 65536    (w_out transposed: wOutT[h][c])
//   qws    [64][2048]    = 131072   (head-major q)
//   skws   [64][2048]    = 131072   (head-major k * 0.125)
//   vws    [64][2048]    = 131072   (head-major v)
//   aws    [2048][64]    = 131072   (attention output, row-major)

__global__ void transpose_kernel(const float* __restrict__ in, float* __restrict__ out,
                                 int rows, int cols) {
    int idx = blockIdx.x * 256 + threadIdx.x;
    int total = rows * cols;
    if (idx < total) {
        int r = idx / cols;
        int c = idx - r * cols;
        out[c * rows + r] = in[idx];
    }
}

// QKV projection: x[2048][1024] * wT[1024][192] -> q/sk/v head-major [64][2048]
// grid 256 (8 rows each), block 384 = 192 features x 2 K-halves.
__global__ __launch_bounds__(384) void qkv_kernel(const float* __restrict__ x,
                                                  const float* __restrict__ wT,
                                                  float* __restrict__ qws,
                                                  float* __restrict__ skws,
                                                  float* __restrict__ vws) {
    __shared__ float part[192][8];
    const int t = threadIdx.x;
    const int kh = (t >= 192) ? 1 : 0;
    const int f = t - kh * 192;
    const int r0 = blockIdx.x * 8;

    const float* xb = x + (size_t)r0 * 1024 + kh * 512;   // wave-uniform base
    const float* wb = wT + (size_t)kh * 512 * 192 + f;    // lane-coalesced

    float acc[8] = {0.f, 0.f, 0.f, 0.f, 0.f, 0.f, 0.f, 0.f};

    for (int kc = 0; kc < 512; kc += 8) {
        float xr[8][8];
#pragma unroll
        for (int r = 0; r < 8; ++r) {
            float4 ta = *(const float4*)(xb + r * 1024 + kc);      // uniform -> s_load
            float4 tb = *(const float4*)(xb + r * 1024 + kc + 4);
            xr[r][0] = ta.x; xr[r][1] = ta.y; xr[r][2] = ta.z; xr[r][3] = ta.w;
            xr[r][4] = tb.x; xr[r][5] = tb.y; xr[r][6] = tb.z; xr[r][7] = tb.w;
        }
#pragma unroll
        for (int u = 0; u < 8; ++u) {
            float wv = wb[(size_t)(kc + u) * 192];                 // coalesced b32
#pragma unroll
            for (int r = 0; r < 8; ++r)
                acc[r] = fmaf(xr[r][u], wv, acc[r]);
        }
    }

    if (kh) {
#pragma unroll
        for (int r = 0; r < 8; ++r) part[f][r] = acc[r];
    }
    __syncthreads();
    if (!kh) {
#pragma unroll
        for (int r = 0; r < 8; ++r) acc[r] += part[f][r];
        const int h = f & 63;
        const int which = f >> 6;  // 0=q 1=k 2=v
        const float scale = (which == 1) ? 0.125f : 1.0f;
        float* dst = (which == 0 ? qws : (which == 1 ? skws : vws)) + (size_t)h * 2048 + r0;
        float4 o0 = make_float4(acc[0] * scale, acc[1] * scale, acc[2] * scale, acc[3] * scale);
        float4 o1 = make_float4(acc[4] * scale, acc[5] * scale, acc[6] * scale, acc[7] * scale);
        *(float4*)(dst) = o0;
        *(float4*)(dst + 4) = o1;
    }
}

// Attention: one wave per (head, 64-row block). 2048 waves = 512 blocks x 4 waves.
// Scores bounded (|s| <~ 1.1 nat) -> no max subtraction needed.
__global__ __launch_bounds__(256) void attn_kernel(const float* __restrict__ qws,
                                                   const float* __restrict__ skws,
                                                   const float* __restrict__ vws,
                                                   float* __restrict__ aws) {
    const int wib = __builtin_amdgcn_readfirstlane((int)(threadIdx.x >> 6));
    const int lane = threadIdx.x & 63;
    const int wid = blockIdx.x * 4 + wib;
    const int h = wid & 63;
    const int rb = 31 - (wid >> 6);   // LPT: longest row-blocks dispatched first
    const int i = rb * 64 + lane;

    const float* skp = skws + (size_t)h * 2048;   // wave-uniform base
    const float* vp  = vws + (size_t)h * 2048;
    const float qv = qws[(size_t)h * 2048 + i];

    const int jb = rb * 64;  // bulk region: j < jb <= i for all lanes (no mask)
    float den0 = 0.f, den1 = 0.f, den2 = 0.f, den3 = 0.f;
    float num0 = 0.f, num1 = 0.f, num2 = 0.f, num3 = 0.f;

    for (int j = 0; j < jb; j += 8) {
        float4 s0 = *(const float4*)(skp + j);      // uniform -> s_load
        float4 s1 = *(const float4*)(skp + j + 4);
        float4 v0 = *(const float4*)(vp + j);
        float4 v1 = *(const float4*)(vp + j + 4);
        float e;
        e = __expf(qv * s0.x); den0 += e; num0 = fmaf(e, v0.x, num0);
        e = __expf(qv * s0.y); den1 += e; num1 = fmaf(e, v0.y, num1);
        e = __expf(qv * s0.z); den2 += e; num2 = fmaf(e, v0.z, num2);
        e = __expf(qv * s0.w); den3 += e; num3 = fmaf(e, v0.w, num3);
        e = __expf(qv * s1.x); den0 += e; num0 = fmaf(e, v1.x, num0);
        e = __expf(qv * s1.y); den1 += e; num1 = fmaf(e, v1.y, num1);
        e = __expf(qv * s1.z); den2 += e; num2 = fmaf(e, v1.z, num2);
        e = __expf(qv * s1.w); den3 += e; num3 = fmaf(e, v1.w, num3);
    }
    // causal tail: j in [jb, jb+64), mask j <= i
    for (int j = jb; j < jb + 64; j += 4) {
        float4 s0 = *(const float4*)(skp + j);
        float4 v0 = *(const float4*)(vp + j);
        float e;
        e = (j     <= i) ? __expf(qv * s0.x) : 0.f; den0 += e; num0 = fmaf(e, v0.x, num0);
        e = (j + 1 <= i) ? __expf(qv * s0.y) : 0.f; den1 += e; num1 = fmaf(e, v0.y, num1);
        e = (j + 2 <= i) ? __expf(qv * s0.z) : 0.f; den2 += e; num2 = fmaf(e, v0.z, num2);
        e = (j + 3 <= i) ? __expf(qv * s0.w) : 0.f; den3 += e; num3 = fmaf(e, v0.w, num3);
    }
    float den = (den0 + den1) + (den2 + den3);
    float num = (num0 + num1) + (num2 + num3);
    aws[(size_t)i * 64 + h] = num / den;
}

// Out projection: out[i][c] = sum_h aws[i][h] * wOutT[h][c].
// grid 512 = 64 row-tiles x 8 col-tiles; block 256; 4x4 micro-tile per thread.
__global__ __launch_bounds__(256) void proj_kernel(const float* __restrict__ aws,
                                                   const float* __restrict__ wOutT,
                                                   float* __restrict__ out) {
    const int t = threadIdx.x;
    const int cg = t & 31;
    const int rg = t >> 5;
    const int r = (blockIdx.x >> 3) * 32 + rg * 4;
    const int c = (blockIdx.x & 7) * 128 + cg * 4;

    float acc[4][4] = {};
    for (int hc = 0; hc < 64; hc += 4) {
        float av[4][4];
#pragma unroll
        for (int rr = 0; rr < 4; ++rr) {
            float4 ta = *(const float4*)(aws + (size_t)(r + rr) * 64 + hc);  // broadcast
            av[rr][0] = ta.x; av[rr][1] = ta.y; av[rr][2] = ta.z; av[rr][3] = ta.w;
        }
#pragma unroll
        for (int hh = 0; hh < 4; ++hh) {
            float4 w4 = *(const float4*)(wOutT + (size_t)(hc + hh) * 1024 + c); // coalesced
#pragma unroll
            for (int rr = 0; rr < 4; ++rr) {
                acc[rr][0] = fmaf(av[rr][hh], w4.x, acc[rr][0]);
                acc[rr][1] = fmaf(av[rr][hh], w4.y, acc[rr][1]);
                acc[rr][2] = fmaf(av[rr][hh], w4.z, acc[rr][2]);
                acc[rr][3] = fmaf(av[rr][hh], w4.w, acc[rr][3]);
            }
        }
    }
#pragma unroll
    for (int rr = 0; rr < 4; ++rr) {
        *(float4*)(out + (size_t)(r + rr) * 1024 + c) =
            make_float4(acc[rr][0], acc[rr][1], acc[rr][2], acc[rr][3]);
    }
}

extern "C" void kernel_launch(void* const* d_in, const int* in_sizes, int n_in,
                              void* d_out, int out_size, void* d_ws, size_t ws_size,
                              hipStream_t stream) {
    const float* x     = (const float*)d_in[0];   // [1,2048,1024]
    const float* w_qkv = (const float*)d_in[1];   // [192,1024]
    const float* w_out = (const float*)d_in[2];   // [1024,64]
    float* out = (float*)d_out;                   // [1,2048,1024]

    float* ws    = (float*)d_ws;
    float* wT    = ws;                 // 196608
    float* wOutT = wT + 196608;        // 65536
    float* qws   = wOutT + 65536;      // 131072
    float* skws  = qws + 131072;       // 131072
    float* vws   = skws + 131072;      // 131072
    float* aws   = vws + 131072;       // 131072

    transpose_kernel<<<dim3(768), dim3(256), 0, stream>>>(w_qkv, wT, 192, 1024);
    transpose_kernel<<<dim3(256), dim3(256), 0, stream>>>(w_out, wOutT, 1024, 64);
    qkv_kernel<<<dim3(256), dim3(384), 0, stream>>>(x, wT, qws, skws, vws);
    attn_kernel<<<dim3(512), dim3(256), 0, stream>>>(qws, skws, vws, aws);
    proj_kernel<<<dim3(512), dim3(256), 0, stream>>>(aws, wOutT, out);
}

// Round 2
// 135.532 us; speedup vs baseline: 1.6125x; 1.6125x over previous
//
#include <hip/hip_runtime.h>

// CausalWanSelfAttention: DIM=1024, 64 heads of head-dim 1, N=2048.
// out[i,c] = sum_h w_out[c,h] * softmax_j<=i( q[i,h]*k[j,h]/8 ) . v[j,h]
//
// Pipeline:
//   transpose w_qkv -> wT[k][f], w_out -> wOutT[h][c]
//   qkv_gemm  (split-K=4, 64x64 tiles)      -> pq[4][192][2048]  (f-major partials)
//   qkv_reduce (sum 4, scale k by 1/8)      -> qws/skws/vws [h][i]
//   attn      (split-j=4, wave per h,rb,c)  -> pn/pd[4][64][2048]
//   attn_reduce (sum 4, divide)             -> aws[h][i]
//   proj      (16x128 tiles)                -> out[i][c]

__global__ void transpose_kernel(const float* __restrict__ in, float* __restrict__ out,
                                 int rows, int cols) {
    int idx = blockIdx.x * 256 + threadIdx.x;
    int total = rows * cols;
    if (idx < total) {
        int r = idx / cols;
        int c = idx - r * cols;
        out[c * rows + r] = in[idx];
    }
}

// C[2048][192] = x[2048][1024] * wT[1024][192], split-K=4 (chunks of 256).
// grid 384 = 32 mtiles * 3 ntiles * 4 ksplit; block 256; micro-tile 4x4.
__global__ __launch_bounds__(256) void qkv_gemm(const float* __restrict__ x,
                                                const float* __restrict__ wT,
                                                float* __restrict__ pq) {
    __shared__ float xsT[32][64];   // [k][row]
    __shared__ float wsld[32][64];  // [k][f]
    const int t = threadIdx.x;
    const int b = blockIdx.x;
    const int ks = b & 3;
    const int nt = (b >> 2) % 3;
    const int mt = b / 12;
    const int i0 = mt * 64;
    const int cb = nt * 64;
    const int k0 = ks * 256;

    const int rf = t & 63;    // staging row (for x) / f (for w)
    const int kq = t >> 6;    // 0..3
    const int tx = t & 15;
    const int ty = t >> 4;

    const float* xp = x + (size_t)(i0 + rf) * 1024 + k0 + kq * 8;
    const float* wp = wT + (size_t)(k0 + kq * 8) * 192 + cb + rf;

    // prefetch step 0
    float4 xa = *(const float4*)(xp);
    float4 xb = *(const float4*)(xp + 4);
    float wr[8];
#pragma unroll
    for (int j = 0; j < 8; ++j) wr[j] = wp[(size_t)j * 192];

    float acc[4][4] = {};

    for (int s = 0; s < 8; ++s) {
        __syncthreads();
        {
            const int kb = kq * 8;
            xsT[kb + 0][rf] = xa.x; xsT[kb + 1][rf] = xa.y;
            xsT[kb + 2][rf] = xa.z; xsT[kb + 3][rf] = xa.w;
            xsT[kb + 4][rf] = xb.x; xsT[kb + 5][rf] = xb.y;
            xsT[kb + 6][rf] = xb.z; xsT[kb + 7][rf] = xb.w;
#pragma unroll
            for (int j = 0; j < 8; ++j) wsld[kb + j][rf] = wr[j];
        }
        __syncthreads();
        if (s < 7) {
            const float* xp2 = xp + (s + 1) * 32;
            xa = *(const float4*)(xp2);
            xb = *(const float4*)(xp2 + 4);
            const float* wp2 = wp + (size_t)(s + 1) * 32 * 192;
#pragma unroll
            for (int j = 0; j < 8; ++j) wr[j] = wp2[(size_t)j * 192];
        }
#pragma unroll
        for (int k = 0; k < 32; ++k) {
            float4 a4 = *(const float4*)&xsT[k][ty * 4];
            float4 b4 = *(const float4*)&wsld[k][tx * 4];
            acc[0][0] = fmaf(a4.x, b4.x, acc[0][0]);
            acc[0][1] = fmaf(a4.x, b4.y, acc[0][1]);
            acc[0][2] = fmaf(a4.x, b4.z, acc[0][2]);
            acc[0][3] = fmaf(a4.x, b4.w, acc[0][3]);
            acc[1][0] = fmaf(a4.y, b4.x, acc[1][0]);
            acc[1][1] = fmaf(a4.y, b4.y, acc[1][1]);
            acc[1][2] = fmaf(a4.y, b4.z, acc[1][2]);
            acc[1][3] = fmaf(a4.y, b4.w, acc[1][3]);
            acc[2][0] = fmaf(a4.z, b4.x, acc[2][0]);
            acc[2][1] = fmaf(a4.z, b4.y, acc[2][1]);
            acc[2][2] = fmaf(a4.z, b4.z, acc[2][2]);
            acc[2][3] = fmaf(a4.z, b4.w, acc[2][3]);
            acc[3][0] = fmaf(a4.w, b4.x, acc[3][0]);
            acc[3][1] = fmaf(a4.w, b4.y, acc[3][1]);
            acc[3][2] = fmaf(a4.w, b4.z, acc[3][2]);
            acc[3][3] = fmaf(a4.w, b4.w, acc[3][3]);
        }
    }

    // write partial, f-major: pq[ks][cb+tx*4+cc][i0+ty*4 .. +3]
    float* pbase = pq + (size_t)ks * 192 * 2048 + (size_t)cb * 2048 + i0;
#pragma unroll
    for (int cc = 0; cc < 4; ++cc) {
        float4 o = make_float4(acc[0][cc], acc[1][cc], acc[2][cc], acc[3][cc]);
        *(float4*)(pbase + (size_t)(tx * 4 + cc) * 2048 + ty * 4) = o;
    }
}

// sum 4 partials, scale k by 1/8, scatter to head-major q/sk/v [h][i]
__global__ __launch_bounds__(256) void qkv_reduce(const float* __restrict__ pq,
                                                  float* __restrict__ qws,
                                                  float* __restrict__ skws,
                                                  float* __restrict__ vws) {
    const int idx = blockIdx.x * 256 + threadIdx.x;   // 98304 threads
    const int f = idx >> 9;                           // 0..191
    const int i = (idx & 511) * 4;
    const size_t S = (size_t)192 * 2048;
    const size_t o = (size_t)f * 2048 + i;
    float4 a0 = *(const float4*)(pq + o);
    float4 a1 = *(const float4*)(pq + S + o);
    float4 a2 = *(const float4*)(pq + 2 * S + o);
    float4 a3 = *(const float4*)(pq + 3 * S + o);
    const int which = f >> 6;
    const float sc = (which == 1) ? 0.125f : 1.0f;
    float4 r = make_float4((a0.x + a1.x + a2.x + a3.x) * sc,
                           (a0.y + a1.y + a2.y + a3.y) * sc,
                           (a0.z + a1.z + a2.z + a3.z) * sc,
                           (a0.w + a1.w + a2.w + a3.w) * sc);
    float* dst = (which == 0) ? qws : (which == 1) ? skws : vws;
    *(float4*)(dst + (size_t)(f & 63) * 2048 + i) = r;
}

// attn: wave = (h, rb, c): 64-row block rb, j-chunk c of 4. 2048 blocks x 4 waves.
// scores bounded (|s| <~ 1.5 nat) -> no max subtraction.
__global__ __launch_bounds__(256) void attn_kernel(const float* __restrict__ qws,
                                                   const float* __restrict__ skws,
                                                   const float* __restrict__ vws,
                                                   float* __restrict__ pn,
                                                   float* __restrict__ pd) {
    const int c = threadIdx.x >> 6;     // j-chunk 0..3
    const int lane = threadIdx.x & 63;
    const int u = blockIdx.x;           // (h, rb)
    const int h = u & 63;
    const int rb = 31 - (u >> 6);       // LPT: long row-blocks first
    const int i = rb * 64 + lane;

    const float* skp = skws + (size_t)h * 2048;
    const float* vp  = vws  + (size_t)h * 2048;
    const float qv = qws[(size_t)h * 2048 + i];

    const int qlen = (rb + 1) * 16;     // chunk length (mult of 16)
    const int jstart = c * qlen;
    const int jend = jstart + qlen;
    const int diag = rb * 64;
    const int bend = (jend < diag) ? jend : diag;
    const int mstart = (jstart > diag) ? jstart : diag;

    float den0 = 0.f, den1 = 0.f, den2 = 0.f, den3 = 0.f;
    float num0 = 0.f, num1 = 0.f, num2 = 0.f, num3 = 0.f;

    for (int j = jstart; j < bend; j += 8) {
        float4 s0 = *(const float4*)(skp + j);
        float4 s1 = *(const float4*)(skp + j + 4);
        float4 v0 = *(const float4*)(vp + j);
        float4 v1 = *(const float4*)(vp + j + 4);
        float e;
        e = __expf(qv * s0.x); den0 += e; num0 = fmaf(e, v0.x, num0);
        e = __expf(qv * s0.y); den1 += e; num1 = fmaf(e, v0.y, num1);
        e = __expf(qv * s0.z); den2 += e; num2 = fmaf(e, v0.z, num2);
        e = __expf(qv * s0.w); den3 += e; num3 = fmaf(e, v0.w, num3);
        e = __expf(qv * s1.x); den0 += e; num0 = fmaf(e, v1.x, num0);
        e = __expf(qv * s1.y); den1 += e; num1 = fmaf(e, v1.y, num1);
        e = __expf(qv * s1.z); den2 += e; num2 = fmaf(e, v1.z, num2);
        e = __expf(qv * s1.w); den3 += e; num3 = fmaf(e, v1.w, num3);
    }
    for (int j = mstart; j < jend; j += 8) {
        float4 s0 = *(const float4*)(skp + j);
        float4 s1 = *(const float4*)(skp + j + 4);
        float4 v0 = *(const float4*)(vp + j);
        float4 v1 = *(const float4*)(vp + j + 4);
        float e;
        e = (j     <= i) ? __expf(qv * s0.x) : 0.f; den0 += e; num0 = fmaf(e, v0.x, num0);
        e = (j + 1 <= i) ? __expf(qv * s0.y) : 0.f; den1 += e; num1 = fmaf(e, v0.y, num1);
        e = (j + 2 <= i) ? __expf(qv * s0.z) : 0.f; den2 += e; num2 = fmaf(e, v0.z, num2);
        e = (j + 3 <= i) ? __expf(qv * s0.w) : 0.f; den3 += e; num3 = fmaf(e, v0.w, num3);
        e = (j + 4 <= i) ? __expf(qv * s1.x) : 0.f; den0 += e; num0 = fmaf(e, v1.x, num0);
        e = (j + 5 <= i) ? __expf(qv * s1.y) : 0.f; den1 += e; num1 = fmaf(e, v1.y, num1);
        e = (j + 6 <= i) ? __expf(qv * s1.z) : 0.f; den2 += e; num2 = fmaf(e, v1.z, num2);
        e = (j + 7 <= i) ? __expf(qv * s1.w) : 0.f; den3 += e; num3 = fmaf(e, v1.w, num3);
    }
    const size_t o = (size_t)(c * 64 + h) * 2048 + i;
    pn[o] = (num0 + num1) + (num2 + num3);
    pd[o] = (den0 + den1) + (den2 + den3);
}

// sum 4 j-chunk partials, divide -> aws[h][i]
__global__ __launch_bounds__(256) void attn_reduce(const float* __restrict__ pn,
                                                   const float* __restrict__ pd,
                                                   float* __restrict__ aws) {
    const int idx = blockIdx.x * 256 + threadIdx.x;   // 32768 threads
    const int h = idx >> 9;
    const int i = (idx & 511) * 4;
    const size_t S = (size_t)64 * 2048;
    const size_t o = (size_t)h * 2048 + i;
    float4 n0 = *(const float4*)(pn + o);
    float4 n1 = *(const float4*)(pn + S + o);
    float4 n2 = *(const float4*)(pn + 2 * S + o);
    float4 n3 = *(const float4*)(pn + 3 * S + o);
    float4 d0 = *(const float4*)(pd + o);
    float4 d1 = *(const float4*)(pd + S + o);
    float4 d2 = *(const float4*)(pd + 2 * S + o);
    float4 d3 = *(const float4*)(pd + 3 * S + o);
    float4 r = make_float4(((n0.x + n1.x) + (n2.x + n3.x)) / ((d0.x + d1.x) + (d2.x + d3.x)),
                           ((n0.y + n1.y) + (n2.y + n3.y)) / ((d0.y + d1.y) + (d2.y + d3.y)),
                           ((n0.z + n1.z) + (n2.z + n3.z)) / ((d0.z + d1.z) + (d2.z + d3.z)),
                           ((n0.w + n1.w) + (n2.w + n3.w)) / ((d0.w + d1.w) + (d2.w + d3.w)));
    *(float4*)(aws + o) = r;
}

// out[i][c] = sum_h aws[h][i] * wOutT[h][c].  grid 1024 = 128 i-tiles x 8 c-tiles.
__global__ __launch_bounds__(256) void proj_kernel(const float* __restrict__ aws,
                                                   const float* __restrict__ wOutT,
                                                   float* __restrict__ out) {
    __shared__ float ast[64][17];
    const int t = threadIdx.x;
    const int i0 = (blockIdx.x >> 3) * 16;
    const int c0 = (blockIdx.x & 7) * 128;

    {
        const int h = t >> 2, iq = t & 3;
        float4 v = *(const float4*)(aws + (size_t)h * 2048 + i0 + iq * 4);
        ast[h][iq * 4 + 0] = v.x; ast[h][iq * 4 + 1] = v.y;
        ast[h][iq * 4 + 2] = v.z; ast[h][iq * 4 + 3] = v.w;
    }
    __syncthreads();

    const int rg = t >> 5;    // 0..7 -> 2 rows each
    const int cg = t & 31;    // 0..31 -> 4 cols each
    const float* wp = wOutT + c0 + cg * 4;
    float acc[2][4] = {};
#pragma unroll 8
    for (int hc = 0; hc < 64; ++hc) {
        float4 w4 = *(const float4*)(wp + (size_t)hc * 1024);
        float a0 = ast[hc][rg * 2];
        float a1 = ast[hc][rg * 2 + 1];
        acc[0][0] = fmaf(a0, w4.x, acc[0][0]);
        acc[0][1] = fmaf(a0, w4.y, acc[0][1]);
        acc[0][2] = fmaf(a0, w4.z, acc[0][2]);
        acc[0][3] = fmaf(a0, w4.w, acc[0][3]);
        acc[1][0] = fmaf(a1, w4.x, acc[1][0]);
        acc[1][1] = fmaf(a1, w4.y, acc[1][1]);
        acc[1][2] = fmaf(a1, w4.z, acc[1][2]);
        acc[1][3] = fmaf(a1, w4.w, acc[1][3]);
    }
#pragma unroll
    for (int rr = 0; rr < 2; ++rr) {
        *(float4*)(out + (size_t)(i0 + rg * 2 + rr) * 1024 + c0 + cg * 4) =
            make_float4(acc[rr][0], acc[rr][1], acc[rr][2], acc[rr][3]);
    }
}

extern "C" void kernel_launch(void* const* d_in, const int* in_sizes, int n_in,
                              void* d_out, int out_size, void* d_ws, size_t ws_size,
                              hipStream_t stream) {
    const float* x     = (const float*)d_in[0];   // [1,2048,1024]
    const float* w_qkv = (const float*)d_in[1];   // [192,1024]
    const float* w_out = (const float*)d_in[2];   // [1024,64]
    float* out = (float*)d_out;                   // [1,2048,1024]

    float* ws    = (float*)d_ws;
    float* wT    = ws;                    // 196608
    float* wOutT = wT + 196608;           // 65536
    float* pq    = wOutT + 65536;         // 4*192*2048 = 1572864
    float* qws   = pq + 1572864;          // 131072
    float* skws  = qws + 131072;          // 131072
    float* vws   = skws + 131072;         // 131072
    float* pn    = vws + 131072;          // 4*64*2048 = 524288
    float* pd    = pn + 524288;           // 524288
    float* aws   = pd + 524288;           // 131072

    transpose_kernel<<<dim3(768), dim3(256), 0, stream>>>(w_qkv, wT, 192, 1024);
    transpose_kernel<<<dim3(256), dim3(256), 0, stream>>>(w_out, wOutT, 1024, 64);
    qkv_gemm<<<dim3(384), dim3(256), 0, stream>>>(x, wT, pq);
    qkv_reduce<<<dim3(384), dim3(256), 0, stream>>>(pq, qws, skws, vws);
    attn_kernel<<<dim3(2048), dim3(256), 0, stream>>>(qws, skws, vws, pn, pd);
    attn_reduce<<<dim3(128), dim3(256), 0, stream>>>(pn, pd, aws);
    proj_kernel<<<dim3(1024), dim3(256), 0, stream>>>(aws, wOutT, out);
}